// Round 1
// baseline (510.291 us; speedup 1.0000x reference)
//
#include <hip/hip_runtime.h>

// BBoxTransform: fused single-pass kernel.
//
// Key insight: the reference's concatenate(axis=0) + reshape(B,N,3,4) scrambles
// pred_boxes. For output (b',n,l,j): flat f = b'*12N + n*12 + l*4 + j over a
// (12B, N) concat array; source row r = f/N, col c = f%N; source array
// k = r/8 in {x1,x2=x1,x3=x4,x4,y1,y2=y4,y3=y1,y4,1,1,1,1}, batch b = r&7.
// A thread's 12 entries are 12 consecutive elements of (usually) one source
// array row; for r>=64 the value is constant 1.0.

__global__ __launch_bounds__(256) void bbox_transform_kernel(
    const float* __restrict__ boxes, const float* __restrict__ deltas,
    float* __restrict__ out, int N, int total)
{
    int idx = blockIdx.x * blockDim.x + threadIdx.x;
    if (idx >= total) return;

    int bp = idx / N;          // b'
    int n  = idx - bp * N;

    // ---- own box: center + rotation ----
    const float* bx = boxes  + (size_t)idx * 5;
    const float* dl = deltas + (size_t)idx * 5;
    float b0 = bx[0], b1 = bx[1], b2 = bx[2], b3 = bx[3], b4 = bx[4];
    float d0 = dl[0], d1 = dl[1], d4 = dl[4];

    float w  = b2 - b0;
    float h  = b3 - b1;
    float cx = b0 + 0.5f * w;
    float cy = b1 + 0.5f * h;
    float pcx = cx + (d0 * 0.1f) * w;
    float pcy = cy + (d1 * 0.1f) * h;
    float pal = atanf(d4) + b4;
    float sa, ca;
    sincosf(pal, &sa, &ca);

    // ---- gather the 12 scrambled pred_boxes entries ----
    int m0 = n * 12;                 // < 3e6, fits int
    int q  = m0 / N;                 // 0..11
    int c0 = m0 - q * N;
    int r0 = bp * 12 + q;

    float P[12];
#pragma unroll
    for (int t = 0; t < 12; ++t) {
        int c = c0 + t;
        int r = r0;
        if (c >= N) { c -= N; r += 1; }
        float v;
        if (r >= 64) {
            v = 1.0f;                                 // the 'ones' blocks
        } else {
            int k = r >> 3;                           // which source array
            int b = r & 7;                            // source batch
            size_t base = ((size_t)b * N + c) * 5;
            int a = (k < 4) ? 0 : 1;                  // x-family vs y-family
            float lo = boxes[base + a];
            float hi = boxes[base + a + 2];
            float dc = deltas[base + a];
            float dd = deltas[base + a + 2];
            float ww  = hi - lo;
            float ctr = lo + 0.5f * ww;
            float pc  = ctr + (dc * 0.1f) * ww;
            float pw  = expf(dd * 0.2f) * ww;
            // plus-sign for k in {2,3,5,7} (x3,x4,y2,y4), minus for {0,1,4,6}
            float s = ((0xAC >> k) & 1) ? 0.5f : -0.5f;
            v = pc + s * pw;
        }
        P[t] = v;
    }

    // ---- bbox_rotated = T @ (R @ (Tinv @ P)), rows 0..1, in ref op order ----
    float r0o[4], r1o[4];
#pragma unroll
    for (int j = 0; j < 4; ++j) {
        float p0 = P[j], p1 = P[4 + j], p2 = P[8 + j];
        float u0 = p0 - pcx * p2;     // Tinv @ P
        float u1 = p1 - pcy * p2;
        float v0 = ca * u0 - sa * u1; // R @ ...
        float v1 = sa * u0 + ca * u1;
        r0o[j] = v0 + pcx * p2;       // T @ ...
        r1o[j] = v1 + pcy * p2;
    }

    // ---- out: (B, N, 4, 2), 8 contiguous floats per (b', n) ----
    float4* op = (float4*)(out + (size_t)idx * 8);
    op[0] = make_float4(r0o[0], r1o[0], r0o[1], r1o[1]);
    op[1] = make_float4(r0o[2], r1o[2], r0o[3], r1o[3]);
}

extern "C" void kernel_launch(void* const* d_in, const int* in_sizes, int n_in,
                              void* d_out, int out_size, void* d_ws, size_t ws_size,
                              hipStream_t stream) {
    const float* boxes  = (const float*)d_in[0];
    const float* deltas = (const float*)d_in[1];
    float* out = (float*)d_out;

    int total = in_sizes[0] / 5;     // B * N
    int N = total / 8;               // B == 8 per setup_inputs
    int threads = 256;
    int blocks = (total + threads - 1) / threads;
    bbox_transform_kernel<<<blocks, threads, 0, stream>>>(boxes, deltas, out, N, total);
}

// Round 2
// 55.055 us; speedup vs baseline: 9.2687x; 9.2687x over previous
//
#include <hip/hip_runtime.h>

// BBoxTransform — two-phase, traffic-minimal.
//
// The reference's concatenate(axis=0)+reshape(B,N,3,4) means
// pred_boxes.flat[f] = concat_row[r][c], r = f/N, c = f%N, where
// concat rows 0..63 are [x1,x2=x1,x3=x4,x4,y1,y2=y4,y3=y1,y4] x 8 batches
// (row r: array k = r/8, batch b = r%8) and rows 64..95 are 1.0.
//
// Phase 1 (fully coalesced): per box compute corners + center + rotation,
// materialize concat rows 0..63 into W (8 coalesced row writes) and
// CTR[idx] = (pcx, pcy, cos a, sin a).
// Phase 2: thread idx reads W[12*idx .. +11] (contiguous, 48B = 3 x float4,
// always 16B aligned) + CTR[idx], applies T*R*Tinv rows 0..1, writes 8 floats.

__global__ __launch_bounds__(256) void bbox_phase1(
    const float* __restrict__ boxes, const float* __restrict__ deltas,
    float* __restrict__ W, float4* __restrict__ CTR, int N, int total)
{
    int idx = blockIdx.x * blockDim.x + threadIdx.x;
    if (idx >= total) return;
    int b = idx / N;
    int c = idx - b * N;

    const float* bx = boxes  + (size_t)idx * 5;
    const float* dl = deltas + (size_t)idx * 5;
    float b0 = bx[0], b1 = bx[1], b2 = bx[2], b3 = bx[3], b4 = bx[4];
    float d0 = dl[0], d1 = dl[1], d2 = dl[2], d3 = dl[3], d4 = dl[4];

    float w  = b2 - b0;
    float h  = b3 - b1;
    float cx = b0 + 0.5f * w;
    float cy = b1 + 0.5f * h;
    float pcx = cx + (d0 * 0.1f) * w;
    float pcy = cy + (d1 * 0.1f) * h;
    float pw  = expf(d2 * 0.2f) * w;
    float ph  = expf(d3 * 0.2f) * h;
    float x1 = pcx - 0.5f * pw, x4 = pcx + 0.5f * pw;
    float y1 = pcy - 0.5f * ph, y4 = pcy + 0.5f * ph;
    float pal = atanf(d4) + b4;
    float sa, ca;
    sincosf(pal, &sa, &ca);

    size_t rs = (size_t)N;
    size_t bc = (size_t)b * rs + c;
    // concat rows: k=0:x1 1:x2=x1 2:x3=x4 3:x4 4:y1 5:y2=y4 6:y3=y1 7:y4
    W[bc + 0 * 8 * rs] = x1;
    W[bc + 1 * 8 * rs] = x1;
    W[bc + 2 * 8 * rs] = x4;
    W[bc + 3 * 8 * rs] = x4;
    W[bc + 4 * 8 * rs] = y1;
    W[bc + 5 * 8 * rs] = y4;
    W[bc + 6 * 8 * rs] = y1;
    W[bc + 7 * 8 * rs] = y4;
    CTR[idx] = make_float4(pcx, pcy, ca, sa);
}

__global__ __launch_bounds__(256) void bbox_phase2(
    const float* __restrict__ W, const float4* __restrict__ CTR,
    float* __restrict__ out, int N, int total)
{
    int idx = blockIdx.x * blockDim.x + threadIdx.x;
    if (idx >= total) return;

    float4 t4 = CTR[idx];
    float pcx = t4.x, pcy = t4.y, ca = t4.z, sa = t4.w;

    long f   = (long)idx * 12;
    long lim = (long)N * 64;

    float P[12];
    if (f + 11 < lim) {
        const float4* wp = (const float4*)(W + f);   // f*4 bytes ≡ 0 mod 16
        float4 a = wp[0], b = wp[1], c = wp[2];
        P[0] = a.x; P[1] = a.y; P[2]  = a.z; P[3]  = a.w;
        P[4] = b.x; P[5] = b.y; P[6]  = b.z; P[7]  = b.w;
        P[8] = c.x; P[9] = c.y; P[10] = c.z; P[11] = c.w;
    } else {
#pragma unroll
        for (int t = 0; t < 12; ++t)
            P[t] = (f + t < lim) ? W[f + t] : 1.0f;
    }

    float r0o[4], r1o[4];
#pragma unroll
    for (int j = 0; j < 4; ++j) {
        float p0 = P[j], p1 = P[4 + j], p2 = P[8 + j];
        float u0 = p0 - pcx * p2;     // Tinv @ P
        float u1 = p1 - pcy * p2;
        float v0 = ca * u0 - sa * u1; // R @ ...
        float v1 = sa * u0 + ca * u1;
        r0o[j] = v0 + pcx * p2;       // T @ ...
        r1o[j] = v1 + pcy * p2;
    }

    float4* op = (float4*)(out + (size_t)idx * 8);
    op[0] = make_float4(r0o[0], r1o[0], r0o[1], r1o[1]);
    op[1] = make_float4(r0o[2], r1o[2], r0o[3], r1o[3]);
}

// ---- fallback (round-1 kernel): used only if ws_size is too small ----
__global__ __launch_bounds__(256) void bbox_fused_fallback(
    const float* __restrict__ boxes, const float* __restrict__ deltas,
    float* __restrict__ out, int N, int total)
{
    int idx = blockIdx.x * blockDim.x + threadIdx.x;
    if (idx >= total) return;
    int bp = idx / N;
    int n  = idx - bp * N;

    const float* bx = boxes  + (size_t)idx * 5;
    const float* dl = deltas + (size_t)idx * 5;
    float b0 = bx[0], b1 = bx[1], b2 = bx[2], b3 = bx[3], b4 = bx[4];
    float d0 = dl[0], d1 = dl[1], d4 = dl[4];
    float w  = b2 - b0, h = b3 - b1;
    float pcx = b0 + 0.5f * w + (d0 * 0.1f) * w;
    float pcy = b1 + 0.5f * h + (d1 * 0.1f) * h;
    float pal = atanf(d4) + b4;
    float sa, ca;
    sincosf(pal, &sa, &ca);

    int m0 = n * 12;
    int q  = m0 / N;
    int c0 = m0 - q * N;
    int r0 = bp * 12 + q;

    float P[12];
#pragma unroll
    for (int t = 0; t < 12; ++t) {
        int c = c0 + t, r = r0;
        if (c >= N) { c -= N; r += 1; }
        float v;
        if (r >= 64) v = 1.0f;
        else {
            int k = r >> 3, b = r & 7;
            size_t base = ((size_t)b * N + c) * 5;
            int a = (k < 4) ? 0 : 1;
            float lo = boxes[base + a], hi = boxes[base + a + 2];
            float dc = deltas[base + a], dd = deltas[base + a + 2];
            float ww = hi - lo;
            float pc = lo + 0.5f * ww + (dc * 0.1f) * ww;
            float pwv = expf(dd * 0.2f) * ww;
            float s = ((0xAC >> k) & 1) ? 0.5f : -0.5f;
            v = pc + s * pwv;
        }
        P[t] = v;
    }

    float r0o[4], r1o[4];
#pragma unroll
    for (int j = 0; j < 4; ++j) {
        float p0 = P[j], p1 = P[4 + j], p2 = P[8 + j];
        float u0 = p0 - pcx * p2, u1 = p1 - pcy * p2;
        float v0 = ca * u0 - sa * u1, v1 = sa * u0 + ca * u1;
        r0o[j] = v0 + pcx * p2;
        r1o[j] = v1 + pcy * p2;
    }
    float4* op = (float4*)(out + (size_t)idx * 8);
    op[0] = make_float4(r0o[0], r1o[0], r0o[1], r1o[1]);
    op[1] = make_float4(r0o[2], r1o[2], r0o[3], r1o[3]);
}

extern "C" void kernel_launch(void* const* d_in, const int* in_sizes, int n_in,
                              void* d_out, int out_size, void* d_ws, size_t ws_size,
                              hipStream_t stream) {
    const float* boxes  = (const float*)d_in[0];
    const float* deltas = (const float*)d_in[1];
    float* out = (float*)d_out;

    int total = in_sizes[0] / 5;     // B * N
    int N = total / 8;               // B == 8
    int threads = 256;
    int blocks = (total + threads - 1) / threads;

    size_t wBytes   = (size_t)64 * N * sizeof(float);     // 64 concat rows
    size_t ctrBytes = (size_t)total * sizeof(float4);
    if (ws_size >= wBytes + ctrBytes) {
        float*  W   = (float*)d_ws;
        float4* CTR = (float4*)((char*)d_ws + wBytes);    // 64MB offset, aligned
        bbox_phase1<<<blocks, threads, 0, stream>>>(boxes, deltas, W, CTR, N, total);
        bbox_phase2<<<blocks, threads, 0, stream>>>(W, CTR, out, N, total);
    } else {
        bbox_fused_fallback<<<blocks, threads, 0, stream>>>(boxes, deltas, out, N, total);
    }
}

// Round 3
// 53.205 us; speedup vs baseline: 9.5911x; 1.0348x over previous
//
#include <hip/hip_runtime.h>

// BBoxTransform — two-phase, dedup + vectorized.
//
// pred_boxes.flat[f] = concat_row[r][c], r=f/N, c=f%N; concat rows 0..63:
// k=r/8 in {x1,x2=x1,x3=x4,x4,y1,y2=y4,y3=y1,y4}, batch b=r%8; rows>=64: 1.0.
// Only 4 distinct corner arrays -> V holds 32 rows: v in {0:x1,1:x4,2:y1,3:y4},
// layout V[(v*8+b)*N + c]. Map: k<4 ? k>>1 : 2+(k&1).
//
// Phase 1: 4 boxes/thread, float4 loads (5 per array) + float4 stores
// (4 corner rows + 4 CTR). Phase 2: 1 box/thread, 3x float4 V read + CTR,
// T*R*Tinv rows 0..1, 2x float4 out.

__global__ __launch_bounds__(256) void bbox_phase1(
    const float* __restrict__ boxes, const float* __restrict__ deltas,
    float* __restrict__ V, float4* __restrict__ CTR, int N, int total)
{
    int t = blockIdx.x * blockDim.x + threadIdx.x;
    int i0 = t * 4;
    if (i0 >= total) return;
    int b = i0 / N;
    int c = i0 - b * N;

    bool fast = (i0 + 3 < total) && (c + 3 < N);   // N%4==0 in practice
    if (fast) {
        const float4* bp = (const float4*)(boxes  + (size_t)i0 * 5);
        const float4* dp = (const float4*)(deltas + (size_t)i0 * 5);
        float4 B0 = bp[0], B1 = bp[1], B2 = bp[2], B3 = bp[3], B4 = bp[4];
        float4 D0 = dp[0], D1 = dp[1], D2 = dp[2], D3 = dp[3], D4 = dp[4];
        float bv[20] = {B0.x,B0.y,B0.z,B0.w, B1.x,B1.y,B1.z,B1.w,
                        B2.x,B2.y,B2.z,B2.w, B3.x,B3.y,B3.z,B3.w,
                        B4.x,B4.y,B4.z,B4.w};
        float dv[20] = {D0.x,D0.y,D0.z,D0.w, D1.x,D1.y,D1.z,D1.w,
                        D2.x,D2.y,D2.z,D2.w, D3.x,D3.y,D3.z,D3.w,
                        D4.x,D4.y,D4.z,D4.w};
        float X1[4], X4[4], Y1[4], Y4[4];
        float4 ctr[4];
#pragma unroll
        for (int j = 0; j < 4; ++j) {
            float b0 = bv[j*5+0], b1 = bv[j*5+1], b2 = bv[j*5+2],
                  b3 = bv[j*5+3], b4 = bv[j*5+4];
            float d0 = dv[j*5+0], d1 = dv[j*5+1], d2 = dv[j*5+2],
                  d3 = dv[j*5+3], d4 = dv[j*5+4];
            float w  = b2 - b0, h = b3 - b1;
            float pcx = b0 + 0.5f * w + (d0 * 0.1f) * w;
            float pcy = b1 + 0.5f * h + (d1 * 0.1f) * h;
            float pw  = expf(d2 * 0.2f) * w;
            float ph  = expf(d3 * 0.2f) * h;
            X1[j] = pcx - 0.5f * pw;  X4[j] = pcx + 0.5f * pw;
            Y1[j] = pcy - 0.5f * ph;  Y4[j] = pcy + 0.5f * ph;
            float pal = atanf(d4) + b4;
            float sa, ca;
            sincosf(pal, &sa, &ca);
            ctr[j] = make_float4(pcx, pcy, ca, sa);
        }
        size_t rs = (size_t)N;
        *(float4*)(V + (size_t)(0*8 + b) * rs + c) = make_float4(X1[0],X1[1],X1[2],X1[3]);
        *(float4*)(V + (size_t)(1*8 + b) * rs + c) = make_float4(X4[0],X4[1],X4[2],X4[3]);
        *(float4*)(V + (size_t)(2*8 + b) * rs + c) = make_float4(Y1[0],Y1[1],Y1[2],Y1[3]);
        *(float4*)(V + (size_t)(3*8 + b) * rs + c) = make_float4(Y4[0],Y4[1],Y4[2],Y4[3]);
        CTR[i0+0] = ctr[0]; CTR[i0+1] = ctr[1];
        CTR[i0+2] = ctr[2]; CTR[i0+3] = ctr[3];
    } else {
#pragma unroll 1
        for (int j = 0; j < 4; ++j) {
            int i = i0 + j;
            if (i >= total) break;
            int bb = i / N, cc = i - bb * N;
            const float* bx = boxes  + (size_t)i * 5;
            const float* dl = deltas + (size_t)i * 5;
            float b0=bx[0],b1=bx[1],b2=bx[2],b3=bx[3],b4=bx[4];
            float d0=dl[0],d1=dl[1],d2=dl[2],d3=dl[3],d4=dl[4];
            float w = b2-b0, h = b3-b1;
            float pcx = b0 + 0.5f*w + (d0*0.1f)*w;
            float pcy = b1 + 0.5f*h + (d1*0.1f)*h;
            float pw = expf(d2*0.2f)*w, ph = expf(d3*0.2f)*h;
            size_t rs = (size_t)N;
            V[(size_t)(0*8+bb)*rs + cc] = pcx - 0.5f*pw;
            V[(size_t)(1*8+bb)*rs + cc] = pcx + 0.5f*pw;
            V[(size_t)(2*8+bb)*rs + cc] = pcy - 0.5f*ph;
            V[(size_t)(3*8+bb)*rs + cc] = pcy + 0.5f*ph;
            float pal = atanf(d4) + b4;
            float sa, ca; sincosf(pal, &sa, &ca);
            CTR[i] = make_float4(pcx, pcy, ca, sa);
        }
    }
}

__global__ __launch_bounds__(256) void bbox_phase2(
    const float* __restrict__ V, const float4* __restrict__ CTR,
    float* __restrict__ out, int N, int total)
{
    int idx = blockIdx.x * blockDim.x + threadIdx.x;
    if (idx >= total) return;

    float4 t4 = CTR[idx];
    float pcx = t4.x, pcy = t4.y, ca = t4.z, sa = t4.w;

    int f = idx * 12;                 // < 24e6, fits int
    int r = f / N;
    int c = f - r * N;

    float P[12];
    if (c + 11 < N && (c & 3) == 0) {         // window within one concat row
        if (r < 64) {
            int k = r >> 3, b = r & 7;
            int v = (k < 4) ? (k >> 1) : (2 + (k & 1));
            const float4* wp = (const float4*)(V + (size_t)(v*8 + b) * N + c);
            float4 a = wp[0], bb = wp[1], cc = wp[2];
            P[0]=a.x; P[1]=a.y; P[2]=a.z;  P[3]=a.w;
            P[4]=bb.x;P[5]=bb.y;P[6]=bb.z; P[7]=bb.w;
            P[8]=cc.x;P[9]=cc.y;P[10]=cc.z;P[11]=cc.w;
        } else {
#pragma unroll
            for (int t = 0; t < 12; ++t) P[t] = 1.0f;
        }
    } else {
#pragma unroll
        for (int t = 0; t < 12; ++t) {
            int ct = c + t, rt = r;
            if (ct >= N) { ct -= N; rt += 1; }
            if (rt >= 64) { P[t] = 1.0f; }
            else {
                int k = rt >> 3, b = rt & 7;
                int v = (k < 4) ? (k >> 1) : (2 + (k & 1));
                P[t] = V[(size_t)(v*8 + b) * N + ct];
            }
        }
    }

    float r0o[4], r1o[4];
#pragma unroll
    for (int j = 0; j < 4; ++j) {
        float p0 = P[j], p1 = P[4 + j], p2 = P[8 + j];
        float u0 = p0 - pcx * p2;     // Tinv @ P
        float u1 = p1 - pcy * p2;
        float v0 = ca * u0 - sa * u1; // R @ ...
        float v1 = sa * u0 + ca * u1;
        r0o[j] = v0 + pcx * p2;       // T @ ...
        r1o[j] = v1 + pcy * p2;
    }

    float4* op = (float4*)(out + (size_t)idx * 8);
    op[0] = make_float4(r0o[0], r1o[0], r0o[1], r1o[1]);
    op[1] = make_float4(r0o[2], r1o[2], r0o[3], r1o[3]);
}

// ---- fallback (fused, no workspace) ----
__global__ __launch_bounds__(256) void bbox_fused_fallback(
    const float* __restrict__ boxes, const float* __restrict__ deltas,
    float* __restrict__ out, int N, int total)
{
    int idx = blockIdx.x * blockDim.x + threadIdx.x;
    if (idx >= total) return;
    int bp = idx / N;
    int n  = idx - bp * N;
    const float* bx = boxes  + (size_t)idx * 5;
    const float* dl = deltas + (size_t)idx * 5;
    float b0=bx[0],b1=bx[1],b2=bx[2],b3=bx[3],b4=bx[4];
    float d0=dl[0],d1=dl[1],d4=dl[4];
    float w=b2-b0, h=b3-b1;
    float pcx = b0+0.5f*w+(d0*0.1f)*w;
    float pcy = b1+0.5f*h+(d1*0.1f)*h;
    float pal = atanf(d4)+b4;
    float sa, ca; sincosf(pal, &sa, &ca);
    int m0 = n*12, q = m0/N, c0 = m0-q*N, r0 = bp*12+q;
    float P[12];
#pragma unroll
    for (int t = 0; t < 12; ++t) {
        int c = c0+t, r = r0;
        if (c >= N) { c -= N; r += 1; }
        float v;
        if (r >= 64) v = 1.0f;
        else {
            int k = r>>3, b = r&7;
            size_t base = ((size_t)b*N + c)*5;
            int a = (k<4)?0:1;
            float lo = boxes[base+a], hi = boxes[base+a+2];
            float dc = deltas[base+a], dd = deltas[base+a+2];
            float ww = hi-lo;
            float pc = lo+0.5f*ww+(dc*0.1f)*ww;
            float pwv = expf(dd*0.2f)*ww;
            float s = ((0xAC>>k)&1)?0.5f:-0.5f;
            v = pc + s*pwv;
        }
        P[t] = v;
    }
    float r0o[4], r1o[4];
#pragma unroll
    for (int j = 0; j < 4; ++j) {
        float p0=P[j], p1=P[4+j], p2=P[8+j];
        float u0=p0-pcx*p2, u1=p1-pcy*p2;
        float v0=ca*u0-sa*u1, v1=sa*u0+ca*u1;
        r0o[j]=v0+pcx*p2; r1o[j]=v1+pcy*p2;
    }
    float4* op = (float4*)(out + (size_t)idx*8);
    op[0] = make_float4(r0o[0],r1o[0],r0o[1],r1o[1]);
    op[1] = make_float4(r0o[2],r1o[2],r0o[3],r1o[3]);
}

extern "C" void kernel_launch(void* const* d_in, const int* in_sizes, int n_in,
                              void* d_out, int out_size, void* d_ws, size_t ws_size,
                              hipStream_t stream) {
    const float* boxes  = (const float*)d_in[0];
    const float* deltas = (const float*)d_in[1];
    float* out = (float*)d_out;

    int total = in_sizes[0] / 5;     // B * N
    int N = total / 8;               // B == 8
    int threads = 256;

    size_t vBytes   = (size_t)32 * N * sizeof(float);     // 32 distinct rows
    size_t ctrBytes = (size_t)total * sizeof(float4);
    if (ws_size >= vBytes + ctrBytes) {
        float*  V   = (float*)d_ws;
        float4* CTR = (float4*)((char*)d_ws + vBytes);    // 32MB offset, aligned
        int t1 = (total + 3) / 4;
        int blocks1 = (t1 + threads - 1) / threads;
        int blocks2 = (total + threads - 1) / threads;
        bbox_phase1<<<blocks1, threads, 0, stream>>>(boxes, deltas, V, CTR, N, total);
        bbox_phase2<<<blocks2, threads, 0, stream>>>(V, CTR, out, N, total);
    } else {
        int blocks = (total + threads - 1) / threads;
        bbox_fused_fallback<<<blocks, threads, 0, stream>>>(boxes, deltas, out, N, total);
    }
}